// Round 3
// baseline (722.468 us; speedup 1.0000x reference)
//
#include <hip/hip_runtime.h>
#include <hip/hip_bf16.h>
#include <math.h>

#define NN 10000
#define NE 160000
#define NZ 10
#define INV_AVG 0.0625f

typedef __attribute__((ext_vector_type(8))) short bf16x8;
typedef __attribute__((ext_vector_type(4))) float f32x4;
typedef __attribute__((ext_vector_type(4))) unsigned short u16x4;
typedef __attribute__((ext_vector_type(8))) unsigned short u16x8;

__device__ __forceinline__ float silu(float x) { return x / (1.0f + expf(-x)); }

__device__ __forceinline__ unsigned short f2b(float f) {
    union { float f; unsigned u; } v; v.f = f;
    unsigned r = v.u + 0x7FFF + ((v.u >> 16) & 1);
    return (unsigned short)(r >> 16);
}
__device__ __forceinline__ float b2f(unsigned short h) {
    union { unsigned u; float f; } v; v.u = ((unsigned)h) << 16; return v.f;
}

// ---------------------------------------------------------------------------
// feats0 = node_attrs @ W_embed ; out[batch[n]] += node_attrs @ atomic_energies
// ---------------------------------------------------------------------------
__global__ __launch_bounds__(256) void node_init(
    const float* __restrict__ attrs, const float* __restrict__ W_embed,
    const float* __restrict__ ae, const int* __restrict__ batch,
    float* __restrict__ feats, float* __restrict__ out)
{
    int gid = blockIdx.x * blockDim.x + threadIdx.x;
    if (gid >= NN * 64) return;
    int n = gid >> 6, k = gid & 63;
    float acc = 0.f;
#pragma unroll
    for (int z = 0; z < NZ; ++z) acc += attrs[n * NZ + z] * W_embed[z * 64 + k];
    feats[gid] = acc;
    if (k == 0) {
        float e0 = 0.f;
#pragma unroll
        for (int z = 0; z < NZ; ++z) e0 += attrs[n * NZ + z] * ae[z];
        atomicAdd(out + batch[n], e0);
    }
}

// ---------------------------------------------------------------------------
// CSR build
// ---------------------------------------------------------------------------
__global__ __launch_bounds__(256) void csr_count(const int* __restrict__ ei, int* __restrict__ cnt)
{
    int e = blockIdx.x * 256 + threadIdx.x;
    if (e < NE) atomicAdd(&cnt[ei[NE + e]], 1);
}

__global__ __launch_bounds__(1024) void csr_scan(const int* __restrict__ cnt, int* __restrict__ row)
{
    __shared__ int part[1024];
    const int tid = threadIdx.x;
    const int base = tid * 10;
    int loc[10];
    int s = 0;
#pragma unroll
    for (int q = 0; q < 10; ++q) {
        int idx = base + q;
        int v = (idx < NN) ? cnt[idx] : 0;
        loc[q] = s; s += v;
    }
    part[tid] = s;
    __syncthreads();
    for (int off = 1; off < 1024; off <<= 1) {
        int v = (tid >= off) ? part[tid - off] : 0;
        __syncthreads();
        part[tid] += v;
        __syncthreads();
    }
    int pre = (tid > 0) ? part[tid - 1] : 0;
#pragma unroll
    for (int q = 0; q < 10; ++q) {
        int idx = base + q;
        if (idx < NN) row[idx] = pre + loc[q];
    }
    if (tid == 1023) row[NN] = part[1023];
}

__global__ __launch_bounds__(256) void csr_scatter(
    const int* __restrict__ ei, const int* __restrict__ row,
    int* __restrict__ cur, int* __restrict__ perm)
{
    int e = blockIdx.x * 256 + threadIdx.x;
    if (e < NE) {
        int r = ei[NE + e];
        int p = atomicAdd(&cur[r], 1);
        perm[row[r] + p] = e;
    }
}

// ---------------------------------------------------------------------------
// w3_prep: pack W3 (f32 [2][64][256]) into bf16 MFMA B-fragments
// layout: w3f[t*16384 + (kk*16+nt)*512 + l*8 + j]  holds W3[t][kk*32+(l>>4)*8+j][nt*16+(l&15)]
// ---------------------------------------------------------------------------
__global__ __launch_bounds__(256) void w3_prep(const float* __restrict__ rW3,
                                               unsigned short* __restrict__ w3f)
{
    int g = blockIdx.x * 256 + threadIdx.x;
    if (g >= 32768) return;
    int t = g >> 14, rem = g & 16383;
    int kk = rem >> 13; int rem2 = rem & 8191;
    int nt = rem2 >> 9; int l = (rem2 >> 3) & 63; int j = rem2 & 7;
    int k = kk * 32 + (l >> 4) * 8 + j;
    int c = nt * 16 + (l & 15);
    w3f[g] = f2b(rW3[t * 16384 + k * 256 + c]);
}

// ---------------------------------------------------------------------------
// edge_mlp: geometry + Y + radial layers 1-3 (f32 math, bf16 LDS activations,
// double-buffered; no register arrays -> no scratch spill). h3 out as bf16.
// LDS layout: sH[(ig*64+lane)*4 + (i&3)]  (ig = i>>2) -> b64 reads, conflict-free.
// ---------------------------------------------------------------------------
__global__ __launch_bounds__(64) void edge_mlp(
    const int* __restrict__ ei, const float* __restrict__ pos,
    const float* __restrict__ W0, const float* __restrict__ W1, const float* __restrict__ W2,
    unsigned short* __restrict__ h3b, float* __restrict__ Yg)
{
    __shared__ unsigned short sHa[4096];
    __shared__ unsigned short sHb[4096];
    const int lane = threadIdx.x;
    const int e = blockIdx.x * 64 + lane;

    const int snd = ei[e], rcv = ei[NE + e];
    const float dx = pos[rcv * 3 + 0] - pos[snd * 3 + 0];
    const float dy = pos[rcv * 3 + 1] - pos[snd * 3 + 1];
    const float dz = pos[rcv * 3 + 2] - pos[snd * 3 + 2];
    const float r = sqrtf(dx * dx + dy * dy + dz * dz + 1e-12f);
    const float ir = 1.0f / r;
    const float x = dx * ir, y = dy * ir, z = dz * ir;
    const float xx = x * x, yy = y * y, zz = z * z;

    {
        float4 y0, y1, y2, y3;
        y0.x = 1.0f;
        y0.y = 1.73205081f * x;
        y0.z = 1.73205081f * y;
        y0.w = 1.73205081f * z;
        y1.x = 3.87298335f * x * y;
        y1.y = 3.87298335f * y * z;
        y1.z = 1.11803399f * (3.0f * zz - 1.0f);
        y1.w = 3.87298335f * x * z;
        y2.x = 1.93649167f * (xx - yy);
        y2.y = 2.09165007f * y * (3.0f * xx - yy);
        y2.z = 10.2469508f * x * y * z;
        y2.w = 1.62018517f * y * (5.0f * zz - 1.0f);
        y3.x = 1.32287566f * z * (5.0f * zz - 3.0f);
        y3.y = 1.62018517f * x * (5.0f * zz - 1.0f);
        y3.z = 5.12347538f * z * (xx - yy);
        y3.w = 2.09165007f * x * (xx - 3.0f * yy);
        float4* Yp = (float4*)(Yg + (size_t)e * 16);
        Yp[0] = y0; Yp[1] = y1; Yp[2] = y2; Yp[3] = y3;
    }

    const float u = r * 0.2f;
    float env = 0.0f;
    if (u < 1.0f) {
        const float u2 = u * u, u5 = u2 * u2 * u;
        env = 1.0f - 21.0f * u5 + 35.0f * u5 * u - 15.0f * u5 * u2;
    }
    const float cb = 0.632455532f * ir * env;
    const float pu = 3.14159265358979f * u;
    float eb[8];
#pragma unroll
    for (int i = 0; i < 8; ++i) eb[i] = cb * sinf((float)(i + 1) * pu);

    // layer 1: 8 -> 64
#pragma unroll
    for (int s = 0; s < 4; ++s) {
        float acc[16];
#pragma unroll
        for (int c = 0; c < 16; ++c) acc[c] = 0.f;
#pragma unroll
        for (int i = 0; i < 8; ++i) {
#pragma unroll
            for (int c = 0; c < 16; ++c) acc[c] += eb[i] * W0[i * 64 + s * 16 + c];
        }
#pragma unroll
        for (int cg = 0; cg < 4; ++cg) {
            u16x4 pk;
#pragma unroll
            for (int q = 0; q < 4; ++q) pk[q] = f2b(silu(acc[cg * 4 + q]));
            *(u16x4*)&sHa[((s * 4 + cg) * 64 + lane) * 4] = pk;
        }
    }

    // layer 2: 64 -> 64 (read sHa, write sHb)
#pragma unroll
    for (int s = 0; s < 4; ++s) {
        float acc[16];
#pragma unroll
        for (int c = 0; c < 16; ++c) acc[c] = 0.f;
#pragma unroll 4
        for (int ig = 0; ig < 16; ++ig) {
            const u16x4 hv4 = *(const u16x4*)&sHa[(ig * 64 + lane) * 4];
#pragma unroll
            for (int q = 0; q < 4; ++q) {
                const float hv = b2f(hv4[q]);
                const int i = ig * 4 + q;
#pragma unroll
                for (int c = 0; c < 16; ++c) acc[c] += hv * W1[i * 64 + s * 16 + c];
            }
        }
#pragma unroll
        for (int cg = 0; cg < 4; ++cg) {
            u16x4 pk;
#pragma unroll
            for (int q = 0; q < 4; ++q) pk[q] = f2b(silu(acc[cg * 4 + q]));
            *(u16x4*)&sHb[((s * 4 + cg) * 64 + lane) * 4] = pk;
        }
    }

    // layer 3: 64 -> 64 (read sHb, write h3 global bf16)
#pragma unroll
    for (int s = 0; s < 4; ++s) {
        float acc[16];
#pragma unroll
        for (int c = 0; c < 16; ++c) acc[c] = 0.f;
#pragma unroll 4
        for (int ig = 0; ig < 16; ++ig) {
            const u16x4 hv4 = *(const u16x4*)&sHb[(ig * 64 + lane) * 4];
#pragma unroll
            for (int q = 0; q < 4; ++q) {
                const float hv = b2f(hv4[q]);
                const int i = ig * 4 + q;
#pragma unroll
                for (int c = 0; c < 16; ++c) acc[c] += hv * W2[i * 64 + s * 16 + c];
            }
        }
        u16x8 o;
#pragma unroll
        for (int q = 0; q < 8; ++q) o[q] = f2b(silu(acc[q]));
        *(u16x8*)&h3b[(size_t)e * 64 + s * 16] = o;
        u16x8 o2;
#pragma unroll
        for (int q = 0; q < 8; ++q) o2[q] = f2b(silu(acc[8 + q]));
        *(u16x8*)&h3b[(size_t)e * 64 + s * 16 + 8] = o2;
    }
}

// ---------------------------------------------------------------------------
// layer4_gemm: Rw[E][256] = h3[E][64] @ W3[64][256], bf16 MFMA 16x16x32.
// One wave per 16-edge m-tile. Output stored bf16 in C-fragment order:
// rwb[((tile*16+nt)*4+jj)*64 + lane]  = C[row=(lane>>4)*4+jj][col=nt*16+(lane&15)]
// ---------------------------------------------------------------------------
__global__ __launch_bounds__(256) void layer4_gemm(
    const unsigned short* __restrict__ h3b, const unsigned short* __restrict__ w3f,
    unsigned short* __restrict__ rwb)
{
    const int w = threadIdx.x >> 6, lane = threadIdx.x & 63;
    const int tile = blockIdx.x * 4 + w;
    const size_t e0 = (size_t)tile * 16;

    const bf16x8 a0 = *(const bf16x8*)&h3b[(e0 + (lane & 15)) * 64 + (lane >> 4) * 8];
    const bf16x8 a1 = *(const bf16x8*)&h3b[(e0 + (lane & 15)) * 64 + 32 + (lane >> 4) * 8];

    f32x4 acc[16];
#pragma unroll
    for (int nt = 0; nt < 16; ++nt) acc[nt] = (f32x4){0.f, 0.f, 0.f, 0.f};

#pragma unroll
    for (int nt = 0; nt < 16; ++nt) {
        const bf16x8 b0 = *(const bf16x8*)&w3f[(nt * 64 + lane) * 8];
        const bf16x8 b1 = *(const bf16x8*)&w3f[((16 + nt) * 64 + lane) * 8];
        acc[nt] = __builtin_amdgcn_mfma_f32_16x16x32_bf16(a0, b0, acc[nt], 0, 0, 0);
        acc[nt] = __builtin_amdgcn_mfma_f32_16x16x32_bf16(a1, b1, acc[nt], 0, 0, 0);
    }

#pragma unroll
    for (int nt = 0; nt < 16; ++nt) {
#pragma unroll
        for (int jj = 0; jj < 4; ++jj) {
            rwb[(((size_t)tile * 16 + nt) * 4 + jj) * 64 + lane] = f2b(acc[nt][jj]);
        }
    }
}

// ---------------------------------------------------------------------------
// gather_update: wave per node. Per edge: one ushort4 Rw load (bf16), Y uniform,
// feats coalesced; then einsum (sA stride-20, conflict-free) + gate + W_out + energy.
// ---------------------------------------------------------------------------
__global__ __launch_bounds__(256) void gather_update(
    const unsigned short* __restrict__ rwb, const float* __restrict__ Yg,
    const int* __restrict__ perm, const int* __restrict__ row,
    const int* __restrict__ ei, const float* __restrict__ feats_in,
    const float* __restrict__ attrs,
    const float* __restrict__ Wmix, const float* __restrict__ Wz,
    const float* __restrict__ Wout, const float* __restrict__ wread1,
    const float* __restrict__ Wr1, const float* __restrict__ wr2,
    const int* __restrict__ batch,
    float* __restrict__ feats_out, float* __restrict__ out, int t)
{
    __shared__ float sA[4][64 * 20];
    __shared__ float sF[4][64];
    const int w = threadIdx.x >> 6;
    const int lane = threadIdx.x & 63;
    const int n = __builtin_amdgcn_readfirstlane(blockIdx.x * 4 + w);
    const int beg = row[n], end = row[n + 1];

    float acc[16];
#pragma unroll
    for (int m = 0; m < 16; ++m) acc[m] = 0.f;

#pragma unroll 2
    for (int g = beg; g < end; ++g) {
        const int e = perm[g];
        const int snd = ei[e];
        const float f = feats_in[(size_t)snd * 64 + lane];
        const unsigned short* rp = rwb +
            ((((size_t)(e >> 4) * 16 + (lane >> 2)) * 4 + (e & 3)) * 64
             + ((e >> 2) & 3) * 16 + (lane & 3) * 4);
        const u16x4 rv = *(const u16x4*)rp;
        const float* Ye = Yg + (size_t)e * 16;
        const float4 y0 = *(const float4*)(Ye + 0);
        const float4 y1 = *(const float4*)(Ye + 4);
        const float4 y2 = *(const float4*)(Ye + 8);
        const float4 y3 = *(const float4*)(Ye + 12);
        const float p0 = f * b2f(rv[0]), p1 = f * b2f(rv[1]);
        const float p2 = f * b2f(rv[2]), p3 = f * b2f(rv[3]);
        acc[0]  += p0 * y0.x;
        acc[1]  += p1 * y0.y;  acc[2]  += p1 * y0.z;  acc[3]  += p1 * y0.w;
        acc[4]  += p2 * y1.x;  acc[5]  += p2 * y1.y;  acc[6]  += p2 * y1.z;
        acc[7]  += p2 * y1.w;  acc[8]  += p2 * y2.x;
        acc[9]  += p3 * y2.y;  acc[10] += p3 * y2.z;  acc[11] += p3 * y2.w;
        acc[12] += p3 * y3.x;  acc[13] += p3 * y3.y;  acc[14] += p3 * y3.z;
        acc[15] += p3 * y3.w;
    }
#pragma unroll
    for (int m = 0; m < 16; ++m) acc[m] *= INV_AVG;

    // A (lane=k) -> LDS, stride 20 floats (bank-conflict-free)
    float* sAw = &sA[w][0];
    {
        float4* v = (float4*)&sAw[lane * 20];
        v[0] = make_float4(acc[0], acc[1], acc[2], acc[3]);
        v[1] = make_float4(acc[4], acc[5], acc[6], acc[7]);
        v[2] = make_float4(acc[8], acc[9], acc[10], acc[11]);
        v[3] = make_float4(acc[12], acc[13], acc[14], acc[15]);
    }

    // einsum: new[m][c] = sum_k A[k][m] * Wmix[l(m)][k][c], lane = c
    float accq[16];
#pragma unroll
    for (int m = 0; m < 16; ++m) accq[m] = 0.f;
    for (int k = 0; k < 64; ++k) {
        const float4 a0 = *(const float4*)&sAw[k * 20 + 0];
        const float4 a1 = *(const float4*)&sAw[k * 20 + 4];
        const float4 a2 = *(const float4*)&sAw[k * 20 + 8];
        const float4 a3 = *(const float4*)&sAw[k * 20 + 12];
        const float wl0 = Wmix[0 * 4096 + k * 64 + lane];
        const float wl1 = Wmix[1 * 4096 + k * 64 + lane];
        const float wl2 = Wmix[2 * 4096 + k * 64 + lane];
        const float wl3 = Wmix[3 * 4096 + k * 64 + lane];
        accq[0]  += a0.x * wl0;
        accq[1]  += a0.y * wl1; accq[2]  += a0.z * wl1; accq[3]  += a0.w * wl1;
        accq[4]  += a1.x * wl2; accq[5]  += a1.y * wl2; accq[6]  += a1.z * wl2;
        accq[7]  += a1.w * wl2; accq[8]  += a2.x * wl2;
        accq[9]  += a2.y * wl3; accq[10] += a2.z * wl3; accq[11] += a2.w * wl3;
        accq[12] += a3.x * wl3; accq[13] += a3.y * wl3; accq[14] += a3.z * wl3;
        accq[15] += a3.w * wl3;
    }

    const float s1 = accq[0];
    float inv2 = 0.f;
#pragma unroll
    for (int m = 0; m < 16; ++m) inv2 += accq[m] * accq[m];

    float z0 = 0.f, z1 = 0.f, z2 = 0.f;
#pragma unroll
    for (int zz = 0; zz < NZ; ++zz) {
        const float a = attrs[n * NZ + zz];
        z0 += a * Wz[(t * 3 + 0) * 640 + zz * 64 + lane];
        z1 += a * Wz[(t * 3 + 1) * 640 + zz * 64 + lane];
        z2 += a * Wz[(t * 3 + 2) * 640 + zz * 64 + lane];
    }
    const float b = z0 * s1 + z1 * inv2 + z2 * (s1 * inv2);

    sF[w][lane] = b;
    float fnew = 0.f;
#pragma unroll 8
    for (int j = 0; j < 64; ++j) fnew += sF[w][j] * Wout[j * 64 + lane];
    feats_out[(size_t)n * 64 + lane] = fnew;

    if (t == 0) {
        float v = fnew * wread1[lane];
#pragma unroll
        for (int off = 32; off > 0; off >>= 1) v += __shfl_down(v, off, 64);
        if (lane == 0) atomicAdd(out + batch[n], v);
    } else {
        sF[w][lane] = fnew;
        if (lane < 16) {
            float a = 0.f;
#pragma unroll 8
            for (int j = 0; j < 64; ++j) a += sF[w][j] * Wr1[j * 16 + lane];
            float vv = silu(a) * wr2[lane];
            vv += __shfl_down(vv, 8, 64);
            vv += __shfl_down(vv, 4, 64);
            vv += __shfl_down(vv, 2, 64);
            vv += __shfl_down(vv, 1, 64);
            if (lane == 0) atomicAdd(out + batch[n], vv);
        }
    }
}

// ---------------------------------------------------------------------------
extern "C" void kernel_launch(void* const* d_in, const int* in_sizes, int n_in,
                              void* d_out, int out_size, void* d_ws, size_t ws_size,
                              hipStream_t stream) {
    const float* attrs   = (const float*)d_in[0];
    const float* pos     = (const float*)d_in[1];
    const int*   ei      = (const int*)d_in[2];
    const int*   batch   = (const int*)d_in[3];
    const float* ae      = (const float*)d_in[4];
    const float* W_embed = (const float*)d_in[5];
    const float* rW0     = (const float*)d_in[6];
    const float* rW1     = (const float*)d_in[7];
    const float* rW2     = (const float*)d_in[8];
    const float* rW3     = (const float*)d_in[9];
    const float* Wmix    = (const float*)d_in[10];
    const float* Wz      = (const float*)d_in[11];
    const float* Wout    = (const float*)d_in[12];
    const float* wread1  = (const float*)d_in[13];
    const float* Wr1     = (const float*)d_in[14];
    const float* wr2     = (const float*)d_in[15];
    float* out = (float*)d_out;

    char* ws = (char*)d_ws;
    unsigned short* rwb  = (unsigned short*)(ws);                 // 81,920,000
    unsigned short* h3b  = (unsigned short*)(ws + 81920000);      // 20,480,000
    float* Yg            = (float*)(ws + 102400000);              // 10,240,000
    float* feats0        = (float*)(ws + 112640000);              //  2,560,000
    float* feats1        = (float*)(ws + 115200000);              //  2,560,000
    unsigned short* w3f  = (unsigned short*)(ws + 117760000);     //     65,536
    int* cnt             = (int*)(ws + 117825536);                //     40,960
    int* cur             = (int*)(ws + 117866496);                //     40,960
    int* rowst           = (int*)(ws + 117907456);                //     40,960
    int* perm            = (int*)(ws + 117948416);                //    640,000

    hipMemsetAsync(out, 0, out_size * sizeof(float), stream);
    hipMemsetAsync(cnt, 0, 81920, stream);   // cnt + cur contiguous

    node_init<<<2500, 256, 0, stream>>>(attrs, W_embed, ae, batch, feats0, out);

    csr_count<<<625, 256, 0, stream>>>(ei, cnt);
    csr_scan<<<1, 1024, 0, stream>>>(cnt, rowst);
    csr_scatter<<<625, 256, 0, stream>>>(ei, rowst, cur, perm);

    w3_prep<<<128, 256, 0, stream>>>(rW3, w3f);

    for (int t = 0; t < 2; ++t) {
        edge_mlp<<<2500, 64, 0, stream>>>(
            ei, pos, rW0 + t * 512, rW1 + t * 4096, rW2 + t * 4096, h3b, Yg);
        layer4_gemm<<<2500, 256, 0, stream>>>(h3b, w3f + t * 16384, rwb);
        gather_update<<<2500, 256, 0, stream>>>(
            rwb, Yg, perm, rowst, ei,
            (t == 0) ? feats0 : feats1, attrs,
            Wmix + t * 16384, Wz, Wout + t * 4096,
            wread1, Wr1, wr2, batch,
            (t == 0) ? feats1 : feats0, out, t);
    }
}

// Round 4
// 563.931 us; speedup vs baseline: 1.2811x; 1.2811x over previous
//
#include <hip/hip_runtime.h>
#include <hip/hip_bf16.h>
#include <math.h>

#define NN 10000
#define NE 160000
#define NZ 10
#define INV_AVG 0.0625f

typedef __attribute__((ext_vector_type(8))) short bf16x8;
typedef __attribute__((ext_vector_type(4))) float f32x4;
typedef __attribute__((ext_vector_type(4))) unsigned short u16x4;
typedef __attribute__((ext_vector_type(8))) unsigned short u16x8;

__device__ __forceinline__ float silu(float x) { return x / (1.0f + expf(-x)); }

__device__ __forceinline__ unsigned short f2b(float f) {
    union { float f; unsigned u; } v; v.f = f;
    unsigned r = v.u + 0x7FFF + ((v.u >> 16) & 1);
    return (unsigned short)(r >> 16);
}
__device__ __forceinline__ float b2f(unsigned short h) {
    union { unsigned u; float f; } v; v.u = ((unsigned)h) << 16; return v.f;
}

// wave-private LDS write->read ordering (no block barrier needed):
#define LDS_FENCE() do { \
    __builtin_amdgcn_sched_barrier(0); \
    asm volatile("s_waitcnt lgkmcnt(0)" ::: "memory"); \
    __builtin_amdgcn_sched_barrier(0); \
} while (0)

// ---------------------------------------------------------------------------
// feats0 = node_attrs @ W_embed ; out[batch[n]] += node_attrs @ atomic_energies
// ---------------------------------------------------------------------------
__global__ __launch_bounds__(256) void node_init(
    const float* __restrict__ attrs, const float* __restrict__ W_embed,
    const float* __restrict__ ae, const int* __restrict__ batch,
    float* __restrict__ feats, float* __restrict__ out)
{
    int gid = blockIdx.x * blockDim.x + threadIdx.x;
    if (gid >= NN * 64) return;
    int n = gid >> 6, k = gid & 63;
    float acc = 0.f;
#pragma unroll
    for (int z = 0; z < NZ; ++z) acc += attrs[n * NZ + z] * W_embed[z * 64 + k];
    feats[gid] = acc;
    if (k == 0) {
        float e0 = 0.f;
#pragma unroll
        for (int z = 0; z < NZ; ++z) e0 += attrs[n * NZ + z] * ae[z];
        atomicAdd(out + batch[n], e0);
    }
}

// ---------------------------------------------------------------------------
// CSR build
// ---------------------------------------------------------------------------
__global__ __launch_bounds__(256) void csr_count(const int* __restrict__ ei, int* __restrict__ cnt)
{
    int e = blockIdx.x * 256 + threadIdx.x;
    if (e < NE) atomicAdd(&cnt[ei[NE + e]], 1);
}

__global__ __launch_bounds__(1024) void csr_scan(const int* __restrict__ cnt, int* __restrict__ row)
{
    __shared__ int part[1024];
    const int tid = threadIdx.x;
    const int base = tid * 10;
    int loc[10];
    int s = 0;
#pragma unroll
    for (int q = 0; q < 10; ++q) {
        int idx = base + q;
        int v = (idx < NN) ? cnt[idx] : 0;
        loc[q] = s; s += v;
    }
    part[tid] = s;
    __syncthreads();
    for (int off = 1; off < 1024; off <<= 1) {
        int v = (tid >= off) ? part[tid - off] : 0;
        __syncthreads();
        part[tid] += v;
        __syncthreads();
    }
    int pre = (tid > 0) ? part[tid - 1] : 0;
#pragma unroll
    for (int q = 0; q < 10; ++q) {
        int idx = base + q;
        if (idx < NN) row[idx] = pre + loc[q];
    }
    if (tid == 1023) row[NN] = part[1023];
}

__global__ __launch_bounds__(256) void csr_scatter(
    const int* __restrict__ ei, const int* __restrict__ row,
    int* __restrict__ cur, int* __restrict__ perm)
{
    int e = blockIdx.x * 256 + threadIdx.x;
    if (e < NE) {
        int r = ei[NE + e];
        int p = atomicAdd(&cur[r], 1);
        perm[row[r] + p] = e;
    }
}

// ---------------------------------------------------------------------------
// w_prep: pack all radial weights into bf16 MFMA B-fragment order.
// Fragment (kt,nt), lane l, elem j holds W[kt*32 + (l>>4)*8 + j][nt*16 + (l&15)].
// w0f: [2][4 frags][512]   (K=8, zero-padded to 32)
// w1f/w2f: [2][8 frags][512]
// w3f: [2][32 frags][512]
// ---------------------------------------------------------------------------
__global__ __launch_bounds__(256) void w_prep(
    const float* __restrict__ rW0, const float* __restrict__ rW1,
    const float* __restrict__ rW2, const float* __restrict__ rW3,
    unsigned short* __restrict__ w0f, unsigned short* __restrict__ w1f,
    unsigned short* __restrict__ w2f, unsigned short* __restrict__ w3f)
{
    int g = blockIdx.x * 256 + threadIdx.x;   // 69632 total
    if (g < 4096) {
        int t = g >> 11, x = g & 2047;
        int nt = x >> 9, l = (x >> 3) & 63, j = x & 7;
        int k = (l >> 4) * 8 + j, c = nt * 16 + (l & 15);
        w0f[g] = (k < 8) ? f2b(rW0[t * 512 + k * 64 + c]) : (unsigned short)0;
    } else if (g < 20480) {
        int x0 = g - 4096;
        int t = x0 >> 13, x = x0 & 8191;
        int fidx = x >> 9, l = (x >> 3) & 63, j = x & 7;
        int kt = fidx >> 2, nt = fidx & 3;
        int k = kt * 32 + (l >> 4) * 8 + j, c = nt * 16 + (l & 15);
        w1f[x0] = f2b(rW1[t * 4096 + k * 64 + c]);
    } else if (g < 36864) {
        int x0 = g - 20480;
        int t = x0 >> 13, x = x0 & 8191;
        int fidx = x >> 9, l = (x >> 3) & 63, j = x & 7;
        int kt = fidx >> 2, nt = fidx & 3;
        int k = kt * 32 + (l >> 4) * 8 + j, c = nt * 16 + (l & 15);
        w2f[x0] = f2b(rW2[t * 4096 + k * 64 + c]);
    } else if (g < 69632) {
        int x0 = g - 36864;
        int t = x0 >> 14, x = x0 & 16383;
        int fidx = x >> 9, l = (x >> 3) & 63, j = x & 7;
        int kt = fidx >> 4, nt = fidx & 15;
        int k = kt * 32 + (l >> 4) * 8 + j, c = nt * 16 + (l & 15);
        w3f[x0] = f2b(rW3[t * 16384 + k * 256 + c]);
    }
}

// ---------------------------------------------------------------------------
// edge_geom (runs ONCE): per edge compute Y (f32) and radial basis eb (bf16).
// ---------------------------------------------------------------------------
__global__ __launch_bounds__(256) void edge_geom(
    const int* __restrict__ ei, const float* __restrict__ pos,
    float* __restrict__ Yg, unsigned short* __restrict__ ebg)
{
    const int e = blockIdx.x * 256 + threadIdx.x;   // grid covers exactly NE
    const int snd = ei[e], rcv = ei[NE + e];
    const float dx = pos[rcv * 3 + 0] - pos[snd * 3 + 0];
    const float dy = pos[rcv * 3 + 1] - pos[snd * 3 + 1];
    const float dz = pos[rcv * 3 + 2] - pos[snd * 3 + 2];
    const float r = sqrtf(dx * dx + dy * dy + dz * dz + 1e-12f);
    const float ir = 1.0f / r;
    const float x = dx * ir, y = dy * ir, z = dz * ir;
    const float xx = x * x, yy = y * y, zz = z * z;

    float4 y0, y1, y2, y3;
    y0.x = 1.0f;
    y0.y = 1.73205081f * x;
    y0.z = 1.73205081f * y;
    y0.w = 1.73205081f * z;
    y1.x = 3.87298335f * x * y;
    y1.y = 3.87298335f * y * z;
    y1.z = 1.11803399f * (3.0f * zz - 1.0f);
    y1.w = 3.87298335f * x * z;
    y2.x = 1.93649167f * (xx - yy);
    y2.y = 2.09165007f * y * (3.0f * xx - yy);
    y2.z = 10.2469508f * x * y * z;
    y2.w = 1.62018517f * y * (5.0f * zz - 1.0f);
    y3.x = 1.32287566f * z * (5.0f * zz - 3.0f);
    y3.y = 1.62018517f * x * (5.0f * zz - 1.0f);
    y3.z = 5.12347538f * z * (xx - yy);
    y3.w = 2.09165007f * x * (xx - 3.0f * yy);
    float4* Yp = (float4*)(Yg + (size_t)e * 16);
    Yp[0] = y0; Yp[1] = y1; Yp[2] = y2; Yp[3] = y3;

    const float u = r * 0.2f;
    float env = 0.0f;
    if (u < 1.0f) {
        const float u2 = u * u, u5 = u2 * u2 * u;
        env = 1.0f - 21.0f * u5 + 35.0f * u5 * u - 15.0f * u5 * u2;
    }
    const float cb = 0.632455532f * ir * env;
    const float pu = 3.14159265358979f * u;
    u16x8 eb;
#pragma unroll
    for (int i = 0; i < 8; ++i) eb[i] = f2b(cb * sinf((float)(i + 1) * pu));
    *(u16x8*)&ebg[(size_t)e * 8] = eb;
}

// ---------------------------------------------------------------------------
// radial_fused: the whole radial MLP (layers 1-4) on the matrix pipe.
// One wave per 64-edge super-tile (4 sub-tiles of 16 edges). Layers 1-3:
// 16x16x32 MFMAs with a per-wave LDS ping/pong bounce ([16][72] bf16,
// 2-way-conflict-free) converting C-layout -> A-layout. Layer 4 streams W3
// B-fragments (L1-resident) and stores Rw bf16 in gather's fragment layout.
// ---------------------------------------------------------------------------
__global__ __launch_bounds__(256, 4) void radial_fused(
    const unsigned short* __restrict__ ebg,
    const unsigned short* __restrict__ w0f,
    const unsigned short* __restrict__ w1f,
    const unsigned short* __restrict__ w2f,
    const unsigned short* __restrict__ w3f,
    unsigned short* __restrict__ rwb)
{
    __shared__ unsigned short sH[4][2][16 * 72];
    const int w = threadIdx.x >> 6, lane = threadIdx.x & 63;
    const int sup = blockIdx.x * 4 + w;
    const int lg = lane >> 4, e16 = lane & 15;

    unsigned short* ping = &sH[w][0][0];
    unsigned short* pong = &sH[w][1][0];

    bf16x8 a4[4][2];

#pragma unroll
    for (int st = 0; st < 4; ++st) {
        const size_t ebase = (size_t)sup * 64 + st * 16;
        f32x4 c[4];

        // ---- layer 1: eb(8, zero-padded) @ W0 ----
        bf16x8 a1 = {0, 0, 0, 0, 0, 0, 0, 0};
        if (lg == 0) a1 = *(const bf16x8*)&ebg[(ebase + e16) * 8];
#pragma unroll
        for (int nt = 0; nt < 4; ++nt) {
            const bf16x8 b = *(const bf16x8*)&w0f[nt * 512 + lane * 8];
            c[nt] = __builtin_amdgcn_mfma_f32_16x16x32_bf16(a1, b, (f32x4){0.f, 0.f, 0.f, 0.f}, 0, 0, 0);
        }
#pragma unroll
        for (int nt = 0; nt < 4; ++nt)
#pragma unroll
            for (int jj = 0; jj < 4; ++jj)
                ping[(lg * 4 + jj) * 72 + nt * 16 + e16] = f2b(silu(c[nt][jj]));
        LDS_FENCE();

        // ---- layer 2 ----
        {
            const bf16x8 ak0 = *(const bf16x8*)&ping[e16 * 72 + lg * 8];
            const bf16x8 ak1 = *(const bf16x8*)&ping[e16 * 72 + 32 + lg * 8];
#pragma unroll
            for (int nt = 0; nt < 4; ++nt) {
                const bf16x8 b0 = *(const bf16x8*)&w1f[nt * 512 + lane * 8];
                const bf16x8 b1 = *(const bf16x8*)&w1f[(4 + nt) * 512 + lane * 8];
                f32x4 acc = __builtin_amdgcn_mfma_f32_16x16x32_bf16(ak0, b0, (f32x4){0.f, 0.f, 0.f, 0.f}, 0, 0, 0);
                c[nt] = __builtin_amdgcn_mfma_f32_16x16x32_bf16(ak1, b1, acc, 0, 0, 0);
            }
        }
#pragma unroll
        for (int nt = 0; nt < 4; ++nt)
#pragma unroll
            for (int jj = 0; jj < 4; ++jj)
                pong[(lg * 4 + jj) * 72 + nt * 16 + e16] = f2b(silu(c[nt][jj]));
        LDS_FENCE();

        // ---- layer 3 ----
        {
            const bf16x8 ak0 = *(const bf16x8*)&pong[e16 * 72 + lg * 8];
            const bf16x8 ak1 = *(const bf16x8*)&pong[e16 * 72 + 32 + lg * 8];
#pragma unroll
            for (int nt = 0; nt < 4; ++nt) {
                const bf16x8 b0 = *(const bf16x8*)&w2f[nt * 512 + lane * 8];
                const bf16x8 b1 = *(const bf16x8*)&w2f[(4 + nt) * 512 + lane * 8];
                f32x4 acc = __builtin_amdgcn_mfma_f32_16x16x32_bf16(ak0, b0, (f32x4){0.f, 0.f, 0.f, 0.f}, 0, 0, 0);
                c[nt] = __builtin_amdgcn_mfma_f32_16x16x32_bf16(ak1, b1, acc, 0, 0, 0);
            }
        }
#pragma unroll
        for (int nt = 0; nt < 4; ++nt)
#pragma unroll
            for (int jj = 0; jj < 4; ++jj)
                ping[(lg * 4 + jj) * 72 + nt * 16 + e16] = f2b(silu(c[nt][jj]));
        LDS_FENCE();

        a4[st][0] = *(const bf16x8*)&ping[e16 * 72 + lg * 8];
        a4[st][1] = *(const bf16x8*)&ping[e16 * 72 + 32 + lg * 8];
        LDS_FENCE();   // order these reads before next subtile's ping writes
    }

    // ---- layer 4: h3 @ W3 -> Rw, stored in gather's fragment layout ----
#pragma unroll 4
    for (int nt = 0; nt < 16; ++nt) {
        const bf16x8 b0 = *(const bf16x8*)&w3f[nt * 512 + lane * 8];
        const bf16x8 b1 = *(const bf16x8*)&w3f[(16 + nt) * 512 + lane * 8];
#pragma unroll
        for (int st = 0; st < 4; ++st) {
            f32x4 cc = __builtin_amdgcn_mfma_f32_16x16x32_bf16(a4[st][0], b0, (f32x4){0.f, 0.f, 0.f, 0.f}, 0, 0, 0);
            cc = __builtin_amdgcn_mfma_f32_16x16x32_bf16(a4[st][1], b1, cc, 0, 0, 0);
            const size_t tile = (size_t)sup * 4 + st;
#pragma unroll
            for (int jj = 0; jj < 4; ++jj)
                rwb[((tile * 16 + nt) * 4 + jj) * 64 + lane] = f2b(cc[jj]);
        }
    }
}

// ---------------------------------------------------------------------------
// gather_update: wave per node (unchanged from round 3).
// ---------------------------------------------------------------------------
__global__ __launch_bounds__(256) void gather_update(
    const unsigned short* __restrict__ rwb, const float* __restrict__ Yg,
    const int* __restrict__ perm, const int* __restrict__ row,
    const int* __restrict__ ei, const float* __restrict__ feats_in,
    const float* __restrict__ attrs,
    const float* __restrict__ Wmix, const float* __restrict__ Wz,
    const float* __restrict__ Wout, const float* __restrict__ wread1,
    const float* __restrict__ Wr1, const float* __restrict__ wr2,
    const int* __restrict__ batch,
    float* __restrict__ feats_out, float* __restrict__ out, int t)
{
    __shared__ float sA[4][64 * 20];
    __shared__ float sF[4][64];
    const int w = threadIdx.x >> 6;
    const int lane = threadIdx.x & 63;
    const int n = __builtin_amdgcn_readfirstlane(blockIdx.x * 4 + w);
    const int beg = row[n], end = row[n + 1];

    float acc[16];
#pragma unroll
    for (int m = 0; m < 16; ++m) acc[m] = 0.f;

#pragma unroll 2
    for (int g = beg; g < end; ++g) {
        const int e = perm[g];
        const int snd = ei[e];
        const float f = feats_in[(size_t)snd * 64 + lane];
        const unsigned short* rp = rwb +
            ((((size_t)(e >> 4) * 16 + (lane >> 2)) * 4 + (e & 3)) * 64
             + ((e >> 2) & 3) * 16 + (lane & 3) * 4);
        const u16x4 rv = *(const u16x4*)rp;
        const float* Ye = Yg + (size_t)e * 16;
        const float4 y0 = *(const float4*)(Ye + 0);
        const float4 y1 = *(const float4*)(Ye + 4);
        const float4 y2 = *(const float4*)(Ye + 8);
        const float4 y3 = *(const float4*)(Ye + 12);
        const float p0 = f * b2f(rv[0]), p1 = f * b2f(rv[1]);
        const float p2 = f * b2f(rv[2]), p3 = f * b2f(rv[3]);
        acc[0]  += p0 * y0.x;
        acc[1]  += p1 * y0.y;  acc[2]  += p1 * y0.z;  acc[3]  += p1 * y0.w;
        acc[4]  += p2 * y1.x;  acc[5]  += p2 * y1.y;  acc[6]  += p2 * y1.z;
        acc[7]  += p2 * y1.w;  acc[8]  += p2 * y2.x;
        acc[9]  += p3 * y2.y;  acc[10] += p3 * y2.z;  acc[11] += p3 * y2.w;
        acc[12] += p3 * y3.x;  acc[13] += p3 * y3.y;  acc[14] += p3 * y3.z;
        acc[15] += p3 * y3.w;
    }
#pragma unroll
    for (int m = 0; m < 16; ++m) acc[m] *= INV_AVG;

    float* sAw = &sA[w][0];
    {
        float4* v = (float4*)&sAw[lane * 20];
        v[0] = make_float4(acc[0], acc[1], acc[2], acc[3]);
        v[1] = make_float4(acc[4], acc[5], acc[6], acc[7]);
        v[2] = make_float4(acc[8], acc[9], acc[10], acc[11]);
        v[3] = make_float4(acc[12], acc[13], acc[14], acc[15]);
    }

    float accq[16];
#pragma unroll
    for (int m = 0; m < 16; ++m) accq[m] = 0.f;
    for (int k = 0; k < 64; ++k) {
        const float4 a0 = *(const float4*)&sAw[k * 20 + 0];
        const float4 a1 = *(const float4*)&sAw[k * 20 + 4];
        const float4 a2 = *(const float4*)&sAw[k * 20 + 8];
        const float4 a3 = *(const float4*)&sAw[k * 20 + 12];
        const float wl0 = Wmix[0 * 4096 + k * 64 + lane];
        const float wl1 = Wmix[1 * 4096 + k * 64 + lane];
        const float wl2 = Wmix[2 * 4096 + k * 64 + lane];
        const float wl3 = Wmix[3 * 4096 + k * 64 + lane];
        accq[0]  += a0.x * wl0;
        accq[1]  += a0.y * wl1; accq[2]  += a0.z * wl1; accq[3]  += a0.w * wl1;
        accq[4]  += a1.x * wl2; accq[5]  += a1.y * wl2; accq[6]  += a1.z * wl2;
        accq[7]  += a1.w * wl2; accq[8]  += a2.x * wl2;
        accq[9]  += a2.y * wl3; accq[10] += a2.z * wl3; accq[11] += a2.w * wl3;
        accq[12] += a3.x * wl3; accq[13] += a3.y * wl3; accq[14] += a3.z * wl3;
        accq[15] += a3.w * wl3;
    }

    const float s1 = accq[0];
    float inv2 = 0.f;
#pragma unroll
    for (int m = 0; m < 16; ++m) inv2 += accq[m] * accq[m];

    float z0 = 0.f, z1 = 0.f, z2 = 0.f;
#pragma unroll
    for (int zz = 0; zz < NZ; ++zz) {
        const float a = attrs[n * NZ + zz];
        z0 += a * Wz[(t * 3 + 0) * 640 + zz * 64 + lane];
        z1 += a * Wz[(t * 3 + 1) * 640 + zz * 64 + lane];
        z2 += a * Wz[(t * 3 + 2) * 640 + zz * 64 + lane];
    }
    const float b = z0 * s1 + z1 * inv2 + z2 * (s1 * inv2);

    sF[w][lane] = b;
    float fnew = 0.f;
#pragma unroll 8
    for (int j = 0; j < 64; ++j) fnew += sF[w][j] * Wout[j * 64 + lane];
    feats_out[(size_t)n * 64 + lane] = fnew;

    if (t == 0) {
        float v = fnew * wread1[lane];
#pragma unroll
        for (int off = 32; off > 0; off >>= 1) v += __shfl_down(v, off, 64);
        if (lane == 0) atomicAdd(out + batch[n], v);
    } else {
        sF[w][lane] = fnew;
        if (lane < 16) {
            float a = 0.f;
#pragma unroll 8
            for (int j = 0; j < 64; ++j) a += sF[w][j] * Wr1[j * 16 + lane];
            float vv = silu(a) * wr2[lane];
            vv += __shfl_down(vv, 8, 64);
            vv += __shfl_down(vv, 4, 64);
            vv += __shfl_down(vv, 2, 64);
            vv += __shfl_down(vv, 1, 64);
            if (lane == 0) atomicAdd(out + batch[n], vv);
        }
    }
}

// ---------------------------------------------------------------------------
extern "C" void kernel_launch(void* const* d_in, const int* in_sizes, int n_in,
                              void* d_out, int out_size, void* d_ws, size_t ws_size,
                              hipStream_t stream) {
    const float* attrs   = (const float*)d_in[0];
    const float* pos     = (const float*)d_in[1];
    const int*   ei      = (const int*)d_in[2];
    const int*   batch   = (const int*)d_in[3];
    const float* ae      = (const float*)d_in[4];
    const float* W_embed = (const float*)d_in[5];
    const float* rW0     = (const float*)d_in[6];
    const float* rW1     = (const float*)d_in[7];
    const float* rW2     = (const float*)d_in[8];
    const float* rW3     = (const float*)d_in[9];
    const float* Wmix    = (const float*)d_in[10];
    const float* Wz      = (const float*)d_in[11];
    const float* Wout    = (const float*)d_in[12];
    const float* wread1  = (const float*)d_in[13];
    const float* Wr1     = (const float*)d_in[14];
    const float* wr2     = (const float*)d_in[15];
    float* out = (float*)d_out;

    char* ws = (char*)d_ws;
    unsigned short* rwb  = (unsigned short*)(ws);                 // 81,920,000
    float* Yg            = (float*)(ws + 81920000);               // 10,240,000
    unsigned short* ebg  = (unsigned short*)(ws + 92160000);      //  2,560,000
    float* feats0        = (float*)(ws + 94720000);               //  2,560,000
    float* feats1        = (float*)(ws + 97280000);               //  2,560,000
    unsigned short* w0f  = (unsigned short*)(ws + 99840000);      //      8,192
    unsigned short* w1f  = (unsigned short*)(ws + 99848192);      //     32,768
    unsigned short* w2f  = (unsigned short*)(ws + 99880960);      //     32,768
    unsigned short* w3f  = (unsigned short*)(ws + 99913728);      //     65,536
    int* cnt             = (int*)(ws + 99979264);                 //     40,960
    int* cur             = (int*)(ws + 100020224);                //     40,960
    int* rowst           = (int*)(ws + 100061184);                //     40,960
    int* perm            = (int*)(ws + 100102144);                //    640,000

    hipMemsetAsync(out, 0, out_size * sizeof(float), stream);
    hipMemsetAsync(cnt, 0, 81920, stream);   // cnt + cur contiguous

    node_init<<<2500, 256, 0, stream>>>(attrs, W_embed, ae, batch, feats0, out);

    csr_count<<<625, 256, 0, stream>>>(ei, cnt);
    csr_scan<<<1, 1024, 0, stream>>>(cnt, rowst);
    csr_scatter<<<625, 256, 0, stream>>>(ei, rowst, cur, perm);

    w_prep<<<272, 256, 0, stream>>>(rW0, rW1, rW2, rW3, w0f, w1f, w2f, w3f);
    edge_geom<<<625, 256, 0, stream>>>(ei, pos, Yg, ebg);

    for (int t = 0; t < 2; ++t) {
        radial_fused<<<625, 256, 0, stream>>>(
            ebg, w0f + t * 2048, w1f + t * 8192, w2f + t * 8192, w3f + t * 16384, rwb);
        gather_update<<<2500, 256, 0, stream>>>(
            rwb, Yg, perm, rowst, ei,
            (t == 0) ? feats0 : feats1, attrs,
            Wmix + t * 16384, Wz, Wout + t * 4096,
            wread1, Wr1, wr2, batch,
            (t == 0) ? feats1 : feats0, out, t);
    }
}

// Round 5
// 509.299 us; speedup vs baseline: 1.4186x; 1.1073x over previous
//
#include <hip/hip_runtime.h>
#include <hip/hip_bf16.h>
#include <math.h>

#define NN 10000
#define NE 160000
#define NZ 10
#define INV_AVG 0.0625f

typedef __attribute__((ext_vector_type(8))) short bf16x8;
typedef __attribute__((ext_vector_type(4))) float f32x4;
typedef __attribute__((ext_vector_type(4))) unsigned short u16x4;
typedef __attribute__((ext_vector_type(8))) unsigned short u16x8;

__device__ __forceinline__ float silu(float x) { return x / (1.0f + expf(-x)); }

__device__ __forceinline__ unsigned short f2b(float f) {
    union { float f; unsigned u; } v; v.f = f;
    unsigned r = v.u + 0x7FFF + ((v.u >> 16) & 1);
    return (unsigned short)(r >> 16);
}
__device__ __forceinline__ float b2f(unsigned short h) {
    union { unsigned u; float f; } v; v.u = ((unsigned)h) << 16; return v.f;
}

// wave-private LDS write->read ordering (no block barrier needed):
#define LDS_FENCE() do { \
    __builtin_amdgcn_sched_barrier(0); \
    asm volatile("s_waitcnt lgkmcnt(0)" ::: "memory"); \
    __builtin_amdgcn_sched_barrier(0); \
} while (0)

// ---------------------------------------------------------------------------
// feats0 = node_attrs @ W_embed ; out[batch[n]] += node_attrs @ atomic_energies
// ---------------------------------------------------------------------------
__global__ __launch_bounds__(256) void node_init(
    const float* __restrict__ attrs, const float* __restrict__ W_embed,
    const float* __restrict__ ae, const int* __restrict__ batch,
    float* __restrict__ feats, float* __restrict__ out)
{
    int gid = blockIdx.x * blockDim.x + threadIdx.x;
    if (gid >= NN * 64) return;
    int n = gid >> 6, k = gid & 63;
    float acc = 0.f;
#pragma unroll
    for (int z = 0; z < NZ; ++z) acc += attrs[n * NZ + z] * W_embed[z * 64 + k];
    feats[gid] = acc;
    if (k == 0) {
        float e0 = 0.f;
#pragma unroll
        for (int z = 0; z < NZ; ++z) e0 += attrs[n * NZ + z] * ae[z];
        atomicAdd(out + batch[n], e0);
    }
}

// ---------------------------------------------------------------------------
// CSR build
// ---------------------------------------------------------------------------
__global__ __launch_bounds__(256) void csr_count(const int* __restrict__ ei, int* __restrict__ cnt)
{
    int e = blockIdx.x * 256 + threadIdx.x;
    if (e < NE) atomicAdd(&cnt[ei[NE + e]], 1);
}

__global__ __launch_bounds__(1024) void csr_scan(const int* __restrict__ cnt, int* __restrict__ row)
{
    __shared__ int part[1024];
    const int tid = threadIdx.x;
    const int base = tid * 10;
    int loc[10];
    int s = 0;
#pragma unroll
    for (int q = 0; q < 10; ++q) {
        int idx = base + q;
        int v = (idx < NN) ? cnt[idx] : 0;
        loc[q] = s; s += v;
    }
    part[tid] = s;
    __syncthreads();
    for (int off = 1; off < 1024; off <<= 1) {
        int v = (tid >= off) ? part[tid - off] : 0;
        __syncthreads();
        part[tid] += v;
        __syncthreads();
    }
    int pre = (tid > 0) ? part[tid - 1] : 0;
#pragma unroll
    for (int q = 0; q < 10; ++q) {
        int idx = base + q;
        if (idx < NN) row[idx] = pre + loc[q];
    }
    if (tid == 1023) row[NN] = part[1023];
}

__global__ __launch_bounds__(256) void csr_scatter(
    const int* __restrict__ ei, const int* __restrict__ row,
    int* __restrict__ cur, int* __restrict__ perm)
{
    int e = blockIdx.x * 256 + threadIdx.x;
    if (e < NE) {
        int r = ei[NE + e];
        int p = atomicAdd(&cur[r], 1);
        perm[row[r] + p] = e;
    }
}

// ---------------------------------------------------------------------------
// w_prep: pack radial weights into bf16 MFMA fragment order (A/B symmetric):
// fragment (kt,nt), lane l, elem j holds W[kt*32 + (l>>4)*8 + j][nt*16 + (l&15)].
// ---------------------------------------------------------------------------
__global__ __launch_bounds__(256) void w_prep(
    const float* __restrict__ rW0, const float* __restrict__ rW1,
    const float* __restrict__ rW2, const float* __restrict__ rW3,
    unsigned short* __restrict__ w0f, unsigned short* __restrict__ w1f,
    unsigned short* __restrict__ w2f, unsigned short* __restrict__ w3f)
{
    int g = blockIdx.x * 256 + threadIdx.x;   // 69632 total
    if (g < 4096) {
        int t = g >> 11, x = g & 2047;
        int nt = x >> 9, l = (x >> 3) & 63, j = x & 7;
        int k = (l >> 4) * 8 + j, c = nt * 16 + (l & 15);
        w0f[g] = (k < 8) ? f2b(rW0[t * 512 + k * 64 + c]) : (unsigned short)0;
    } else if (g < 20480) {
        int x0 = g - 4096;
        int t = x0 >> 13, x = x0 & 8191;
        int fidx = x >> 9, l = (x >> 3) & 63, j = x & 7;
        int kt = fidx >> 2, nt = fidx & 3;
        int k = kt * 32 + (l >> 4) * 8 + j, c = nt * 16 + (l & 15);
        w1f[x0] = f2b(rW1[t * 4096 + k * 64 + c]);
    } else if (g < 36864) {
        int x0 = g - 20480;
        int t = x0 >> 13, x = x0 & 8191;
        int fidx = x >> 9, l = (x >> 3) & 63, j = x & 7;
        int kt = fidx >> 2, nt = fidx & 3;
        int k = kt * 32 + (l >> 4) * 8 + j, c = nt * 16 + (l & 15);
        w2f[x0] = f2b(rW2[t * 4096 + k * 64 + c]);
    } else if (g < 69632) {
        int x0 = g - 36864;
        int t = x0 >> 14, x = x0 & 16383;
        int fidx = x >> 9, l = (x >> 3) & 63, j = x & 7;
        int kt = fidx >> 4, nt = fidx & 15;
        int k = kt * 32 + (l >> 4) * 8 + j, c = nt * 16 + (l & 15);
        w3f[x0] = f2b(rW3[t * 16384 + k * 256 + c]);
    }
}

// ---------------------------------------------------------------------------
// edge_geom (runs ONCE): per PERMUTED edge slot g, compute Y (f32), radial
// basis eb (bf16), and sender index. All outputs in receiver-sorted order.
// ---------------------------------------------------------------------------
__global__ __launch_bounds__(256) void edge_geom(
    const int* __restrict__ ei, const float* __restrict__ pos,
    const int* __restrict__ perm,
    float* __restrict__ Yg, unsigned short* __restrict__ ebg,
    int* __restrict__ snd_p)
{
    const int g = blockIdx.x * 256 + threadIdx.x;   // grid covers exactly NE
    const int e = perm[g];
    const int snd = ei[e], rcv = ei[NE + e];
    snd_p[g] = snd;
    const float dx = pos[rcv * 3 + 0] - pos[snd * 3 + 0];
    const float dy = pos[rcv * 3 + 1] - pos[snd * 3 + 1];
    const float dz = pos[rcv * 3 + 2] - pos[snd * 3 + 2];
    const float r = sqrtf(dx * dx + dy * dy + dz * dz + 1e-12f);
    const float ir = 1.0f / r;
    const float x = dx * ir, y = dy * ir, z = dz * ir;
    const float xx = x * x, yy = y * y, zz = z * z;

    float4 y0, y1, y2, y3;
    y0.x = 1.0f;
    y0.y = 1.73205081f * x;
    y0.z = 1.73205081f * y;
    y0.w = 1.73205081f * z;
    y1.x = 3.87298335f * x * y;
    y1.y = 3.87298335f * y * z;
    y1.z = 1.11803399f * (3.0f * zz - 1.0f);
    y1.w = 3.87298335f * x * z;
    y2.x = 1.93649167f * (xx - yy);
    y2.y = 2.09165007f * y * (3.0f * xx - yy);
    y2.z = 10.2469508f * x * y * z;
    y2.w = 1.62018517f * y * (5.0f * zz - 1.0f);
    y3.x = 1.32287566f * z * (5.0f * zz - 3.0f);
    y3.y = 1.62018517f * x * (5.0f * zz - 1.0f);
    y3.z = 5.12347538f * z * (xx - yy);
    y3.w = 2.09165007f * x * (xx - 3.0f * yy);
    float4* Yp = (float4*)(Yg + (size_t)g * 16);
    Yp[0] = y0; Yp[1] = y1; Yp[2] = y2; Yp[3] = y3;

    const float u = r * 0.2f;
    float env = 0.0f;
    if (u < 1.0f) {
        const float u2 = u * u, u5 = u2 * u2 * u;
        env = 1.0f - 21.0f * u5 + 35.0f * u5 * u - 15.0f * u5 * u2;
    }
    const float cb = 0.632455532f * ir * env;
    const float pu = 3.14159265358979f * u;
    u16x8 eb;
#pragma unroll
    for (int i = 0; i < 8; ++i) eb[i] = f2b(cb * sinf((float)(i + 1) * pu));
    *(u16x8*)&ebg[(size_t)g * 8] = eb;
}

// ---------------------------------------------------------------------------
// radial_fused: whole radial MLP on the matrix pipe. ONE 16-edge tile per
// wave (10000 waves). Layers 1-3: 16x16x32 MFMAs + per-wave LDS ping/pong
// ([16][72] bf16) converting C-layout -> A-layout. Layer 4 uses the operand
// SWAP trick (W3^T @ h3^T): A/B fragment packings are symmetric, and the
// transposed C-fragment makes each lane's 4 outputs contiguous in rwb[g][c]
// -> direct coalescable u16x4 global stores, no LDS transpose.
// ---------------------------------------------------------------------------
__global__ __launch_bounds__(256) void radial_fused(
    const unsigned short* __restrict__ ebg,
    const unsigned short* __restrict__ w0f,
    const unsigned short* __restrict__ w1f,
    const unsigned short* __restrict__ w2f,
    const unsigned short* __restrict__ w3f,
    unsigned short* __restrict__ rwb)
{
    __shared__ unsigned short sP[4][2][16 * 72];
    const int w = threadIdx.x >> 6, lane = threadIdx.x & 63;
    const int tIdx = blockIdx.x * 4 + w;          // 16-edge tile id
    const int lg = lane >> 4, e16 = lane & 15;
    unsigned short* ping = &sP[w][0][0];
    unsigned short* pong = &sP[w][1][0];

    const size_t g0 = (size_t)tIdx * 16;
    f32x4 c[4];

    // ---- layer 1: eb(8, zero-padded to 32) @ W0 ----
    bf16x8 a1 = {0, 0, 0, 0, 0, 0, 0, 0};
    if (lg == 0) a1 = *(const bf16x8*)&ebg[(g0 + e16) * 8];
#pragma unroll
    for (int nt = 0; nt < 4; ++nt) {
        const bf16x8 b = *(const bf16x8*)&w0f[nt * 512 + lane * 8];
        c[nt] = __builtin_amdgcn_mfma_f32_16x16x32_bf16(a1, b, (f32x4){0.f, 0.f, 0.f, 0.f}, 0, 0, 0);
    }
#pragma unroll
    for (int nt = 0; nt < 4; ++nt)
#pragma unroll
        for (int jj = 0; jj < 4; ++jj)
            ping[(lg * 4 + jj) * 72 + nt * 16 + e16] = f2b(silu(c[nt][jj]));
    LDS_FENCE();

    // ---- layer 2 ----
    {
        const bf16x8 ak0 = *(const bf16x8*)&ping[e16 * 72 + lg * 8];
        const bf16x8 ak1 = *(const bf16x8*)&ping[e16 * 72 + 32 + lg * 8];
#pragma unroll
        for (int nt = 0; nt < 4; ++nt) {
            const bf16x8 b0 = *(const bf16x8*)&w1f[nt * 512 + lane * 8];
            const bf16x8 b1 = *(const bf16x8*)&w1f[(4 + nt) * 512 + lane * 8];
            f32x4 acc = __builtin_amdgcn_mfma_f32_16x16x32_bf16(ak0, b0, (f32x4){0.f, 0.f, 0.f, 0.f}, 0, 0, 0);
            c[nt] = __builtin_amdgcn_mfma_f32_16x16x32_bf16(ak1, b1, acc, 0, 0, 0);
        }
    }
    LDS_FENCE();   // order layer-2 ping reads before pong writes share pipe cleanly
#pragma unroll
    for (int nt = 0; nt < 4; ++nt)
#pragma unroll
        for (int jj = 0; jj < 4; ++jj)
            pong[(lg * 4 + jj) * 72 + nt * 16 + e16] = f2b(silu(c[nt][jj]));
    LDS_FENCE();

    // ---- layer 3 ----
    {
        const bf16x8 ak0 = *(const bf16x8*)&pong[e16 * 72 + lg * 8];
        const bf16x8 ak1 = *(const bf16x8*)&pong[e16 * 72 + 32 + lg * 8];
#pragma unroll
        for (int nt = 0; nt < 4; ++nt) {
            const bf16x8 b0 = *(const bf16x8*)&w2f[nt * 512 + lane * 8];
            const bf16x8 b1 = *(const bf16x8*)&w2f[(4 + nt) * 512 + lane * 8];
            f32x4 acc = __builtin_amdgcn_mfma_f32_16x16x32_bf16(ak0, b0, (f32x4){0.f, 0.f, 0.f, 0.f}, 0, 0, 0);
            c[nt] = __builtin_amdgcn_mfma_f32_16x16x32_bf16(ak1, b1, acc, 0, 0, 0);
        }
    }
    LDS_FENCE();
#pragma unroll
    for (int nt = 0; nt < 4; ++nt)
#pragma unroll
        for (int jj = 0; jj < 4; ++jj)
            ping[(lg * 4 + jj) * 72 + nt * 16 + e16] = f2b(silu(c[nt][jj]));
    LDS_FENCE();

    // ---- layer 4 (swapped): Rw^T tile = W3^T @ h3^T ----
    const bf16x8 h0 = *(const bf16x8*)&ping[e16 * 72 + lg * 8];
    const bf16x8 h1 = *(const bf16x8*)&ping[e16 * 72 + 32 + lg * 8];
#pragma unroll 4
    for (int nt = 0; nt < 16; ++nt) {
        const bf16x8 b0 = *(const bf16x8*)&w3f[nt * 512 + lane * 8];
        const bf16x8 b1 = *(const bf16x8*)&w3f[(16 + nt) * 512 + lane * 8];
        f32x4 cc = __builtin_amdgcn_mfma_f32_16x16x32_bf16(b0, h0, (f32x4){0.f, 0.f, 0.f, 0.f}, 0, 0, 0);
        cc = __builtin_amdgcn_mfma_f32_16x16x32_bf16(b1, h1, cc, 0, 0, 0);
        // lane holds c = nt*16 + lg*4 + jj (jj=0..3 contiguous) for edge g0+e16
        u16x4 o;
#pragma unroll
        for (int jj = 0; jj < 4; ++jj) o[jj] = f2b(cc[jj]);
        *(u16x4*)&rwb[(g0 + e16) * 256 + nt * 16 + lg * 4] = o;
    }
}

// ---------------------------------------------------------------------------
// gather_update: wave per node. All edge streams (rwb, Yg, snd_p) are
// receiver-sorted -> pure sequential reads; only feats[snd] is scattered
// (L2-resident). 4-edge software-pipelined batches.
// ---------------------------------------------------------------------------
__global__ __launch_bounds__(256) void gather_update(
    const unsigned short* __restrict__ rwb, const float* __restrict__ Yg,
    const int* __restrict__ row, const int* __restrict__ snd_p,
    const float* __restrict__ feats_in, const float* __restrict__ attrs,
    const float* __restrict__ Wmix, const float* __restrict__ Wz,
    const float* __restrict__ Wout, const float* __restrict__ wread1,
    const float* __restrict__ Wr1, const float* __restrict__ wr2,
    const int* __restrict__ batch,
    float* __restrict__ feats_out, float* __restrict__ out, int t)
{
    __shared__ float sA[4][64 * 20];
    __shared__ float sF[4][64];
    const int w = threadIdx.x >> 6;
    const int lane = threadIdx.x & 63;
    const int n = __builtin_amdgcn_readfirstlane(blockIdx.x * 4 + w);
    const int beg = row[n], end = row[n + 1];

    float acc[16];
#pragma unroll
    for (int m = 0; m < 16; ++m) acc[m] = 0.f;

    int g = beg;
    for (; g + 4 <= end; g += 4) {
        u16x4 rv[4]; float f[4];
        float4 ya[4], yb[4], yc[4], yd[4];
#pragma unroll
        for (int j = 0; j < 4; ++j) {
            const int gg = g + j;
            rv[j] = *(const u16x4*)&rwb[(size_t)gg * 256 + lane * 4];
            f[j] = feats_in[(size_t)snd_p[gg] * 64 + lane];
            const float* Ye = Yg + (size_t)gg * 16;
            ya[j] = *(const float4*)(Ye + 0);
            yb[j] = *(const float4*)(Ye + 4);
            yc[j] = *(const float4*)(Ye + 8);
            yd[j] = *(const float4*)(Ye + 12);
        }
#pragma unroll
        for (int j = 0; j < 4; ++j) {
            const float p0 = f[j] * b2f(rv[j][0]), p1 = f[j] * b2f(rv[j][1]);
            const float p2 = f[j] * b2f(rv[j][2]), p3 = f[j] * b2f(rv[j][3]);
            acc[0]  += p0 * ya[j].x;
            acc[1]  += p1 * ya[j].y;  acc[2]  += p1 * ya[j].z;  acc[3]  += p1 * ya[j].w;
            acc[4]  += p2 * yb[j].x;  acc[5]  += p2 * yb[j].y;  acc[6]  += p2 * yb[j].z;
            acc[7]  += p2 * yb[j].w;  acc[8]  += p2 * yc[j].x;
            acc[9]  += p3 * yc[j].y;  acc[10] += p3 * yc[j].z;  acc[11] += p3 * yc[j].w;
            acc[12] += p3 * yd[j].x;  acc[13] += p3 * yd[j].y;  acc[14] += p3 * yd[j].z;
            acc[15] += p3 * yd[j].w;
        }
    }
    for (; g < end; ++g) {
        const u16x4 rv = *(const u16x4*)&rwb[(size_t)g * 256 + lane * 4];
        const float f = feats_in[(size_t)snd_p[g] * 64 + lane];
        const float* Ye = Yg + (size_t)g * 16;
        const float4 y0 = *(const float4*)(Ye + 0);
        const float4 y1 = *(const float4*)(Ye + 4);
        const float4 y2 = *(const float4*)(Ye + 8);
        const float4 y3 = *(const float4*)(Ye + 12);
        const float p0 = f * b2f(rv[0]), p1 = f * b2f(rv[1]);
        const float p2 = f * b2f(rv[2]), p3 = f * b2f(rv[3]);
        acc[0]  += p0 * y0.x;
        acc[1]  += p1 * y0.y;  acc[2]  += p1 * y0.z;  acc[3]  += p1 * y0.w;
        acc[4]  += p2 * y1.x;  acc[5]  += p2 * y1.y;  acc[6]  += p2 * y1.z;
        acc[7]  += p2 * y1.w;  acc[8]  += p2 * y2.x;
        acc[9]  += p3 * y2.y;  acc[10] += p3 * y2.z;  acc[11] += p3 * y2.w;
        acc[12] += p3 * y3.x;  acc[13] += p3 * y3.y;  acc[14] += p3 * y3.z;
        acc[15] += p3 * y3.w;
    }
#pragma unroll
    for (int m = 0; m < 16; ++m) acc[m] *= INV_AVG;

    float* sAw = &sA[w][0];
    {
        float4* v = (float4*)&sAw[lane * 20];
        v[0] = make_float4(acc[0], acc[1], acc[2], acc[3]);
        v[1] = make_float4(acc[4], acc[5], acc[6], acc[7]);
        v[2] = make_float4(acc[8], acc[9], acc[10], acc[11]);
        v[3] = make_float4(acc[12], acc[13], acc[14], acc[15]);
    }

    float accq[16];
#pragma unroll
    for (int m = 0; m < 16; ++m) accq[m] = 0.f;
    for (int k = 0; k < 64; ++k) {
        const float4 a0 = *(const float4*)&sAw[k * 20 + 0];
        const float4 a1 = *(const float4*)&sAw[k * 20 + 4];
        const float4 a2 = *(const float4*)&sAw[k * 20 + 8];
        const float4 a3 = *(const float4*)&sAw[k * 20 + 12];
        const float wl0 = Wmix[0 * 4096 + k * 64 + lane];
        const float wl1 = Wmix[1 * 4096 + k * 64 + lane];
        const float wl2 = Wmix[2 * 4096 + k * 64 + lane];
        const float wl3 = Wmix[3 * 4096 + k * 64 + lane];
        accq[0]  += a0.x * wl0;
        accq[1]  += a0.y * wl1; accq[2]  += a0.z * wl1; accq[3]  += a0.w * wl1;
        accq[4]  += a1.x * wl2; accq[5]  += a1.y * wl2; accq[6]  += a1.z * wl2;
        accq[7]  += a1.w * wl2; accq[8]  += a2.x * wl2;
        accq[9]  += a2.y * wl3; accq[10] += a2.z * wl3; accq[11] += a2.w * wl3;
        accq[12] += a3.x * wl3; accq[13] += a3.y * wl3; accq[14] += a3.z * wl3;
        accq[15] += a3.w * wl3;
    }

    const float s1 = accq[0];
    float inv2 = 0.f;
#pragma unroll
    for (int m = 0; m < 16; ++m) inv2 += accq[m] * accq[m];

    float z0 = 0.f, z1 = 0.f, z2 = 0.f;
#pragma unroll
    for (int zz = 0; zz < NZ; ++zz) {
        const float a = attrs[n * NZ + zz];
        z0 += a * Wz[(t * 3 + 0) * 640 + zz * 64 + lane];
        z1 += a * Wz[(t * 3 + 1) * 640 + zz * 64 + lane];
        z2 += a * Wz[(t * 3 + 2) * 640 + zz * 64 + lane];
    }
    const float b = z0 * s1 + z1 * inv2 + z2 * (s1 * inv2);

    sF[w][lane] = b;
    float fnew = 0.f;
#pragma unroll 8
    for (int j = 0; j < 64; ++j) fnew += sF[w][j] * Wout[j * 64 + lane];
    feats_out[(size_t)n * 64 + lane] = fnew;

    if (t == 0) {
        float v = fnew * wread1[lane];
#pragma unroll
        for (int off = 32; off > 0; off >>= 1) v += __shfl_down(v, off, 64);
        if (lane == 0) atomicAdd(out + batch[n], v);
    } else {
        sF[w][lane] = fnew;
        if (lane < 16) {
            float a = 0.f;
#pragma unroll 8
            for (int j = 0; j < 64; ++j) a += sF[w][j] * Wr1[j * 16 + lane];
            float vv = silu(a) * wr2[lane];
            vv += __shfl_down(vv, 8, 64);
            vv += __shfl_down(vv, 4, 64);
            vv += __shfl_down(vv, 2, 64);
            vv += __shfl_down(vv, 1, 64);
            if (lane == 0) atomicAdd(out + batch[n], vv);
        }
    }
}

// ---------------------------------------------------------------------------
extern "C" void kernel_launch(void* const* d_in, const int* in_sizes, int n_in,
                              void* d_out, int out_size, void* d_ws, size_t ws_size,
                              hipStream_t stream) {
    const float* attrs   = (const float*)d_in[0];
    const float* pos     = (const float*)d_in[1];
    const int*   ei      = (const int*)d_in[2];
    const int*   batch   = (const int*)d_in[3];
    const float* ae      = (const float*)d_in[4];
    const float* W_embed = (const float*)d_in[5];
    const float* rW0     = (const float*)d_in[6];
    const float* rW1     = (const float*)d_in[7];
    const float* rW2     = (const float*)d_in[8];
    const float* rW3     = (const float*)d_in[9];
    const float* Wmix    = (const float*)d_in[10];
    const float* Wz      = (const float*)d_in[11];
    const float* Wout    = (const float*)d_in[12];
    const float* wread1  = (const float*)d_in[13];
    const float* Wr1     = (const float*)d_in[14];
    const float* wr2     = (const float*)d_in[15];
    float* out = (float*)d_out;

    char* ws = (char*)d_ws;
    unsigned short* rwb  = (unsigned short*)(ws);                 // [NE][256] bf16 = 81,920,000
    float* Yg            = (float*)(ws + 81920000);               // [NE][16] f32  = 10,240,000
    unsigned short* ebg  = (unsigned short*)(ws + 92160000);      // [NE][8] bf16  =  2,560,000
    float* feats0        = (float*)(ws + 94720000);               //  2,560,000
    float* feats1        = (float*)(ws + 97280000);               //  2,560,000
    unsigned short* w0f  = (unsigned short*)(ws + 99840000);      //      8,192
    unsigned short* w1f  = (unsigned short*)(ws + 99848192);      //     32,768
    unsigned short* w2f  = (unsigned short*)(ws + 99880960);      //     32,768
    unsigned short* w3f  = (unsigned short*)(ws + 99913728);      //     65,536
    int* cnt             = (int*)(ws + 99979264);                 //     40,960
    int* cur             = (int*)(ws + 100020224);                //     40,960
    int* rowst           = (int*)(ws + 100061184);                //     40,960
    int* perm            = (int*)(ws + 100102144);                //    640,000
    int* snd_p           = (int*)(ws + 100742144);                //    640,000

    hipMemsetAsync(out, 0, out_size * sizeof(float), stream);
    hipMemsetAsync(cnt, 0, 81920, stream);   // cnt + cur contiguous

    node_init<<<2500, 256, 0, stream>>>(attrs, W_embed, ae, batch, feats0, out);

    csr_count<<<625, 256, 0, stream>>>(ei, cnt);
    csr_scan<<<1, 1024, 0, stream>>>(cnt, rowst);
    csr_scatter<<<625, 256, 0, stream>>>(ei, rowst, cur, perm);

    w_prep<<<272, 256, 0, stream>>>(rW0, rW1, rW2, rW3, w0f, w1f, w2f, w3f);
    edge_geom<<<625, 256, 0, stream>>>(ei, pos, perm, Yg, ebg, snd_p);

    for (int t = 0; t < 2; ++t) {
        radial_fused<<<2500, 256, 0, stream>>>(
            ebg, w0f + t * 2048, w1f + t * 8192, w2f + t * 8192, w3f + t * 16384, rwb);
        gather_update<<<2500, 256, 0, stream>>>(
            rwb, Yg, rowst, snd_p,
            (t == 0) ? feats0 : feats1, attrs,
            Wmix + t * 16384, Wz, Wout + t * 4096,
            wread1, Wr1, wr2, batch,
            (t == 0) ? feats1 : feats0, out, t);
    }
}